// Round 2
// baseline (129.259 us; speedup 1.0000x reference)
//
#include <hip/hip_runtime.h>

// SpatiallyVariantConvolution: out[b,c,y,x] = sum_{i,j} feat_pad[b,c,y+i,x+j] * ker[b,i,j,y,x]
// b=4, c=96, h=w=256, k=7, pad=3, fp32. Taps shared across all 96 channels.

#define BATCH 4
#define CHAN 96
#define HW_ 256
#define HWPIX 65536
#define KS 7
#define PADR 3
#define TW 32
#define TH 32
#define PXT 4             // y-pixels owned per thread
#define CG 4              // channels staged per iteration (float4 in LDS)
#define NCQ (CHAN / CG)   // 24
#define HALO 38           // TW + KS - 1 = TH + KS - 1
#define PLANE (HALO * HALO)        // 1444 pixel slots (float4 each)
#define STAGE_DW (PLANE * CG)      // 5776 dwords = 23.1 KB
#define NTHR 256
#define SPT 23                     // ceil(STAGE_DW / NTHR)

__global__ __launch_bounds__(NTHR, 1)
void svconv_kernel(const float* __restrict__ K_, const float* __restrict__ F_,
                   float* __restrict__ O_) {
    __shared__ float lds[STAGE_DW];   // single buffer; pipelining lives in registers

    const int tid = threadIdx.x;
    const int xt = blockIdx.x, yt = blockIdx.y, b = blockIdx.z;
    const int tx  = tid & 31;          // 0..31 (x within tile)
    const int ty  = tid >> 5;          // 0..7  (y-quad index)
    const int gx  = xt * TW + tx;
    const int gy0 = yt * TH + ty * PXT;

    // ---- per-pixel taps in registers for the whole kernel; taps whose feature
    // source falls outside the image are zeroed (padding), so staging below can
    // clamp addresses freely and never needs per-iteration masking.
    float kr[PXT][KS][KS];
#pragma unroll
    for (int s = 0; s < PXT; ++s)
#pragma unroll
        for (int i = 0; i < KS; ++i)
#pragma unroll
            for (int j = 0; j < KS; ++j) {
                float v = K_[((((size_t)b * KS + i) * KS + j) * HW_ + (gy0 + s)) * HW_ + gx];
                const int fy = gy0 + s + i - PADR;
                const int fx = gx + j - PADR;
                kr[s][i][j] = ((unsigned)fy < (unsigned)HW_ && (unsigned)fx < (unsigned)HW_) ? v : 0.0f;
            }

    // ---- iteration-invariant staged-load byte offsets (clamped into the image)
    unsigned voff[SPT];
#pragma unroll
    for (int t = 0; t < SPT; ++t) {
        int idx = t * NTHR + tid;
        if (idx >= STAGE_DW) idx = STAGE_DW - 1;   // tail lanes load a dup (write is guarded)
        const int c  = idx & (CG - 1);
        const int ps = idx >> 2;                   // pixel slot (ry, rx) in halo
        const int ry = ps / HALO;
        const int rx = ps - ry * HALO;
        int fy = yt * TH + ry - PADR; fy = fy < 0 ? 0 : (fy > HW_ - 1 ? HW_ - 1 : fy);
        int fx = xt * TW + rx - PADR; fx = fx < 0 ? 0 : (fx > HW_ - 1 ? HW_ - 1 : fx);
        voff[t] = (unsigned)((c * HWPIX + fy * HW_ + fx) * 4);
    }

    const char* fb = (const char*)(F_ + (size_t)b * CHAN * HWPIX);

    // prologue: issue stage loads for quad 0
    float rbuf[SPT];
#pragma unroll
    for (int t = 0; t < SPT; ++t)
        rbuf[t] = *(const float*)(fb + voff[t]);

#pragma unroll 1
    for (int cq = 0; cq < NCQ; ++cq) {
        // write staged quad to LDS (vmcnt wait on rbuf inserted by compiler;
        // loads have been in flight since last iteration's compute phase)
#pragma unroll
        for (int t = 0; t < SPT; ++t) {
            const int idx = t * NTHR + tid;
            if (idx < STAGE_DW) lds[idx] = rbuf[t];
        }

        // issue next quad's loads now; they fly under this quad's compute
        if (cq + 1 < NCQ) {
            const char* fb2 = fb + (size_t)(cq + 1) * CG * HWPIX * 4;
#pragma unroll
            for (int t = 0; t < SPT; ++t)
                rbuf[t] = *(const float*)(fb2 + voff[t]);
        }

        __syncthreads();   // staged quad visible

        const float4* L = (const float4*)lds;
        float acc[PXT][CG];
#pragma unroll
        for (int s = 0; s < PXT; ++s)
#pragma unroll
            for (int q = 0; q < CG; ++q) acc[s][q] = 0.0f;

#pragma unroll
        for (int roff = 0; roff < PXT + KS - 1; ++roff) {   // 10 window rows
            const int rb = (ty * PXT + roff) * HALO + tx;
#pragma unroll
            for (int rxo = 0; rxo < KS; ++rxo) {
                const float4 w = L[rb + rxo];
#pragma unroll
                for (int s = 0; s < PXT; ++s) {
                    const int i = roff - s;
                    if (i >= 0 && i < KS) {
                        const float k = kr[s][i][rxo];
                        acc[s][0] += w.x * k;
                        acc[s][1] += w.y * k;
                        acc[s][2] += w.z * k;
                        acc[s][3] += w.w * k;
                    }
                }
            }
        }

        // coalesced stores (consecutive gx across lanes)
        float* ob = O_ + (size_t)b * CHAN * HWPIX + (size_t)cq * CG * HWPIX
                  + (size_t)gy0 * HW_ + gx;
#pragma unroll
        for (int q = 0; q < CG; ++q)
#pragma unroll
            for (int s = 0; s < PXT; ++s)
                ob[(size_t)q * HWPIX + s * HW_] = acc[s][q];

        __syncthreads();   // all reads done before next iteration's LDS writes
    }
}

extern "C" void kernel_launch(void* const* d_in, const int* in_sizes, int n_in,
                              void* d_out, int out_size, void* d_ws, size_t ws_size,
                              hipStream_t stream) {
    const float* kernels  = (const float*)d_in[0];  // [4,7,7,256,256]
    const float* features = (const float*)d_in[1];  // [4,96,256,256]
    float* out = (float*)d_out;                     // [4,96,256,256]

    dim3 grid(HW_ / TW, HW_ / TH, BATCH);  // (8, 8, 4) = 256 blocks = 1/CU
    dim3 block(NTHR);
    svconv_kernel<<<grid, block, 0, stream>>>(kernels, features, out);
}

// Round 3
// 105.737 us; speedup vs baseline: 1.2224x; 1.2224x over previous
//
#include <hip/hip_runtime.h>

// out[b,c,y,x] = sum_{dy,dx} f[b,c,y+dy-3,x+dx-3] * ker[b,dy,dx,y,x]
// MFMA formulation: per 16-pixel x-strip, per y, per dy:
//   D[m=c][n=px] += A[m][k] * B[k][n],  A[m][k]=fbf[c0+m, y+dy-3, xwin0+k],
//   B[k][n] = bf16(ker[dy, k-n, y, x0+n]) if 0<=k-n<=6 else 0.
#define BATCH 4
#define CHAN 96
#define HW_ 256
#define HWPIX 65536
#define KS 7
#define XT 64              // x-strip per block (4 n-tiles of 16)
#define YT 16              // y rows per block
#define NTHR 512           // 8 waves: wave = ch*4 + nt
#define XWIN 72            // staged x window: gx0-3 .. gx0+68
#define XPITCH 88          // shorts per (row,c) line (pad stays 0)
#define ROWS 8
#define ROWSTRIDE_S (CHAN * XPITCH)   // 8448 shorts
#define RING_S (ROWS * ROWSTRIDE_S)   // 67584 shorts = 135168 B
#define NPAIR (XWIN / 2)              // 36
#define SLOTS (CHAN * NPAIR)          // 3456
#define SPT 7

typedef __attribute__((ext_vector_type(8))) short short8v;
typedef __attribute__((ext_vector_type(4))) float f32x4;

static __device__ __forceinline__ unsigned short f2bf(float x) {
    union { float f; unsigned u; } v; v.f = x;
    unsigned u = v.u + 0x7fffu + ((v.u >> 16) & 1u);
    return (unsigned short)(u >> 16);
}

__global__ __launch_bounds__(NTHR)
void svconv_mfma(const float* __restrict__ K_, const float* __restrict__ F_,
                 float* __restrict__ O_) {
    extern __shared__ short lds[];   // RING_S shorts

    const int tid = threadIdx.x;
    const int xt = blockIdx.x, yt = blockIdx.y, b = blockIdx.z;
    const int gx0 = xt * XT, gy0 = yt * YT;
    const int wave = tid >> 6, lane = tid & 63;
    const int nt = wave & 3, ch = wave >> 2;      // n-tile 0..3, c-half 0..1
    const int n = lane & 15, kb = lane >> 4;      // B: col n, k-block kb

    // ---- zero LDS once (pad columns MUST be 0 forever; stale LDS may be NaN)
    unsigned* lds32 = (unsigned*)lds;
#pragma unroll
    for (int i = 0; i < RING_S / 2 / NTHR; ++i) lds32[tid + NTHR * i] = 0u;
    __syncthreads();

    // ---- staging slot precompute (iteration-invariant)
    int ldsoff[SPT];   // short offset within a row plane, -1 = idle slot
    int gof[SPT];      // c*HWPIX + x0e   (x0e = gx0-3+xi0)
    int m0[SPT], m1[SPT];
#pragma unroll
    for (int i = 0; i < SPT; ++i) {
        int idx = tid + NTHR * i;
        if (idx < SLOTS) {
            int c = idx / NPAIR;
            int xi0 = 2 * (idx - c * NPAIR);
            int x0e = gx0 - 3 + xi0;
            ldsoff[i] = c * XPITCH + xi0;
            gof[i] = c * HWPIX + x0e;
            m0[i] = ((unsigned)x0e < (unsigned)HW_);
            m1[i] = ((unsigned)(x0e + 1) < (unsigned)HW_);
        } else { ldsoff[i] = -1; gof[i] = 0; m0[i] = 0; m1[i] = 0; }
    }
    const float* Fb = F_ + (size_t)b * CHAN * HWPIX;

    // ---- prologue: stage rows gy0-3 .. gy0+3 (OOB rows/pixels -> 0)
    for (int r = -3; r <= 3; ++r) {
        int yr = gy0 + r;
        int yok = ((unsigned)yr < (unsigned)HW_);
        int rbase = (yr & 7) * ROWSTRIDE_S;
#pragma unroll
        for (int i = 0; i < SPT; ++i) {
            if (ldsoff[i] >= 0) {
                float f0 = 0.f, f1 = 0.f;
                if (yok && m0[i]) f0 = Fb[(size_t)yr * HW_ + gof[i]];
                if (yok && m1[i]) f1 = Fb[(size_t)yr * HW_ + gof[i] + 1];
                lds32[(rbase + ldsoff[i]) >> 1] =
                    (unsigned)f2bf(f0) | ((unsigned)f2bf(f1) << 16);
            }
        }
    }

    // ---- prefetch row gy0+4 into registers
    float r0[SPT], r1[SPT];
    {
        int yr = gy0 + 4;
        int yok = ((unsigned)yr < (unsigned)HW_);
#pragma unroll
        for (int i = 0; i < SPT; ++i) {
            r0[i] = 0.f; r1[i] = 0.f;
            if (yok && m0[i]) r0[i] = Fb[(size_t)yr * HW_ + gof[i]];
            if (yok && m1[i]) r1[i] = Fb[(size_t)yr * HW_ + gof[i] + 1];
        }
    }

    const int dxb = kb * 8 - n;
    const float* Kb = K_ + (size_t)b * KS * KS * HWPIX + gx0 + nt * 16 + n;

    for (int t = 0; t < YT; ++t) {
        const int y = gy0 + t;

        // ---- build B fragments for row y in registers (7 dy)
        short8v bf[KS];
        const float* Kp = Kb + (size_t)y * HW_;
#pragma unroll
        for (int dy = 0; dy < KS; ++dy) {
            short8v f;
#pragma unroll
            for (int j = 0; j < 8; ++j) {
                int dx = dxb + j;
                float v = 0.f;
                if ((unsigned)dx <= 6u) v = Kp[(size_t)(dy * KS + dx) * HWPIX];
                f[j] = (short)f2bf(v);
            }
            bf[dy] = f;
        }

        // ---- barrier: drain LDS ops only; global loads stay in flight (T4)
        asm volatile("s_waitcnt lgkmcnt(0)" ::: "memory");
        __builtin_amdgcn_s_barrier();

        // ---- write prefetched row y+4 into ring slot (y+4)&7
        {
            int rbase = ((y + 4) & 7) * ROWSTRIDE_S;
#pragma unroll
            for (int i = 0; i < SPT; ++i)
                if (ldsoff[i] >= 0)
                    lds32[(rbase + ldsoff[i]) >> 1] =
                        (unsigned)f2bf(r0[i]) | ((unsigned)f2bf(r1[i]) << 16);
        }

        // ---- issue next prefetch (row y+5); flies under compute below
        {
            int yr = y + 5;
            int yok = ((unsigned)yr < (unsigned)HW_);
#pragma unroll
            for (int i = 0; i < SPT; ++i) {
                r0[i] = 0.f; r1[i] = 0.f;
                if (yok && m0[i]) r0[i] = Fb[(size_t)yr * HW_ + gof[i]];
                if (yok && m1[i]) r1[i] = Fb[(size_t)yr * HW_ + gof[i] + 1];
            }
        }

        // ---- compute: 3 c-tiles x 7 dy MFMAs, acc chained over dy
        f32x4 acc[3];
#pragma unroll
        for (int ct = 0; ct < 3; ++ct) acc[ct] = f32x4{0.f, 0.f, 0.f, 0.f};

#pragma unroll
        for (int dy = 0; dy < KS; ++dy) {
            const int rs = (y + dy - 3) & 7;
            const int abase = rs * ROWSTRIDE_S + (ch * 48 + (lane & 15)) * XPITCH
                            + nt * 16 + kb * 8;
#pragma unroll
            for (int ct = 0; ct < 3; ++ct) {
                short8v a = *(const short8v*)(lds + abase + ct * 16 * XPITCH);
                acc[ct] = __builtin_amdgcn_mfma_f32_16x16x32_bf16(a, bf[dy], acc[ct], 0, 0, 0);
            }
        }

        // ---- store: D col = lane&15 (pixel), row = (lane>>4)*4 + r (channel)
        {
            const int px = gx0 + nt * 16 + (lane & 15);
            const int crow = (lane >> 4) * 4;
#pragma unroll
            for (int ct = 0; ct < 3; ++ct) {
                const int c0 = ch * 48 + ct * 16 + crow;
#pragma unroll
                for (int r = 0; r < 4; ++r)
                    O_[((size_t)(b * CHAN + c0 + r)) * HWPIX + (size_t)y * HW_ + px] = acc[ct][r];
            }
        }
    }
}

extern "C" void kernel_launch(void* const* d_in, const int* in_sizes, int n_in,
                              void* d_out, int out_size, void* d_ws, size_t ws_size,
                              hipStream_t stream) {
    const float* kernels  = (const float*)d_in[0];  // [4,7,7,256,256]
    const float* features = (const float*)d_in[1];  // [4,96,256,256]
    float* out = (float*)d_out;                     // [4,96,256,256]

    const size_t shmem = RING_S * sizeof(short);    // 135168 B
    hipFuncSetAttribute(reinterpret_cast<const void*>(&svconv_mfma),
                        hipFuncAttributeMaxDynamicSharedMemorySize, (int)shmem);

    dim3 grid(HW_ / XT, HW_ / YT, BATCH);  // (4, 16, 4) = 256 blocks
    dim3 block(NTHR);
    svconv_mfma<<<grid, block, shmem, stream>>>(kernels, features, out);
}

// Round 4
// 74.740 us; speedup vs baseline: 1.7294x; 1.4147x over previous
//
#include <hip/hip_runtime.h>

// out[b,c,y,x] = sum_{dy,dx} f[b,c,y+dy-3,x+dx-3] * ker[b,dy,dx,y,x]
// MFMA per 16-px strip: D[m=c][n=px] += A[m][k] * B[k][n];
//   A[m][k] = fbf[c0+m, y+dy-3, gx0-3+nt*16+k]  (feature ring in LDS)
//   B[k][n] = bf16(ker[dy, k-n, y, gx0+nt*16+n]) for k-n in [0,6], else 0
// B is pre-built in LDS (BT) from coalesced K loads; band k in [n, n+6] <= 21,
// so kb=3 lanes (k 24..31) supply constant zero fragments.

#define BATCH 4
#define CHAN 96
#define HW_ 256
#define HWPIX 65536
#define KS 7
#define XT 64
#define YT 16
#define NTHR 512
#define XPITCH 72                    // shorts per (row,c); 144 B, 16B-aligned
#define ROWSTRIDE (CHAN * XPITCH)    // 6912 shorts
#define RING_S (8 * ROWSTRIDE)       // 55296 shorts = 110592 B
#define NPAIR 36                     // XWIN=72 px staged as 36 pairs
#define FSLOTS (CHAN * NPAIR)        // 3456
#define FSPT 7
#define BT_K 24                      // stored k-dim (band max 21, pad to 24)
#define BT_NROW (KS * BT_K)          // 168 shorts per n (336 B)
#define BT_STRIP (16 * BT_NROW)      // 2688
#define BT_BUF (4 * BT_STRIP)        // 10752 shorts per buffer
#define KVALS (KS * KS * XT)         // 3136
#define KSPT 7
#define LDS_BYTES ((RING_S + 2 * BT_BUF) * 2)   // 153600 B

typedef __attribute__((ext_vector_type(8))) short short8v;
typedef __attribute__((ext_vector_type(4))) float f32x4;

static __device__ __forceinline__ unsigned short f2bf(float x) {
    union { float f; unsigned u; } v; v.f = x;
    unsigned u = v.u + 0x7fffu + ((v.u >> 16) & 1u);
    return (unsigned short)(u >> 16);
}

__global__ __launch_bounds__(NTHR)
void svconv_mfma2(const float* __restrict__ K_, const float* __restrict__ F_,
                  float* __restrict__ O_) {
    extern __shared__ short lds[];
    unsigned* lds32 = (unsigned*)lds;
    short* BT = lds + RING_S;

    const int tid = threadIdx.x;
    const int xt = blockIdx.x, yt = blockIdx.y, b = blockIdx.z;
    const int gx0 = xt * XT, gy0 = yt * YT;
    const int wave = tid >> 6, lane = tid & 63;
    const int nt = wave & 3, ch = wave >> 2;   // n-strip 0..3, c-half 0..1
    const int n = lane & 15, kb = lane >> 4;   // frag col / k-group

    // ---- zero both BT buffers once: non-band slots must stay 0 forever
    {
        unsigned* bt32 = (unsigned*)BT;        // 2*BT_BUF shorts = 10752 dwords
#pragma unroll
        for (int i = 0; i < BT_BUF / NTHR; ++i)   // 21 exact
            bt32[tid + NTHR * i] = 0u;
    }

    // ---- feature staging slots (iteration-invariant); ring writes are
    // dword-linear in idx -> conflict-free
    int fldsoff[FSPT], fgof[FSPT];
    bool fm0[FSPT], fm1[FSPT];
#pragma unroll
    for (int i = 0; i < FSPT; ++i) {
        int idx = tid + NTHR * i;
        if (idx < FSLOTS) {
            int c = idx / NPAIR;
            int xi0 = 2 * (idx - c * NPAIR);
            int x0e = gx0 - 3 + xi0;           // window origin gx0-3
            fldsoff[i] = c * XPITCH + xi0;
            fgof[i] = c * HWPIX + x0e;         // unclamped; loads are guarded
            fm0[i] = ((unsigned)x0e < (unsigned)HW_);
            fm1[i] = ((unsigned)(x0e + 1) < (unsigned)HW_);
        } else { fldsoff[i] = -1; fgof[i] = 0; fm0[i] = false; fm1[i] = false; }
    }

    // ---- K staging slots: coalesced source (one 256B run per wave-slot),
    // scattered 2B band writes BT[nt][n][dy][n+dx]
    int kgoff[KSPT], kldsoff[KSPT];
#pragma unroll
    for (int i = 0; i < KSPT; ++i) {
        int idx = tid + NTHR * i;
        if (idx < KVALS) {
            int dydx = idx >> 6, xl = idx & 63;
            int dy = dydx / KS, dx = dydx - KS * dy;
            int sn = xl & 15, snt = xl >> 4;
            kgoff[i] = dydx * HWPIX + gx0 + xl;
            kldsoff[i] = snt * BT_STRIP + sn * BT_NROW + dy * BT_K + (sn + dx);
        } else { kgoff[i] = 0; kldsoff[i] = -1; }
    }

    const float* Fb = F_ + (size_t)b * CHAN * HWPIX;
    const float* Kb = K_ + (size_t)b * KS * KS * HWPIX;

    __syncthreads();   // BT zeros visible before band writes

    // ---- prologue: ring rows gy0-3..gy0+3 (OOB -> 0)
    for (int r = -3; r <= 3; ++r) {
        int yr = gy0 + r;
        bool yok = ((unsigned)yr < (unsigned)HW_);
        int rbase = (yr & 7) * ROWSTRIDE;
#pragma unroll
        for (int i = 0; i < FSPT; ++i) {
            if (fldsoff[i] >= 0) {
                float f0 = 0.f, f1 = 0.f;
                if (yok && fm0[i]) f0 = Fb[(size_t)yr * HW_ + fgof[i]];
                if (yok && fm1[i]) f1 = Fb[(size_t)yr * HW_ + fgof[i] + 1];
                lds32[(rbase + fldsoff[i]) >> 1] =
                    (unsigned)f2bf(f0) | ((unsigned)f2bf(f1) << 16);
            }
        }
    }
    // ---- prologue: K row gy0 -> BT buf 0
#pragma unroll
    for (int i = 0; i < KSPT; ++i)
        if (kldsoff[i] >= 0)
            BT[kldsoff[i]] = (short)f2bf(Kb[kgoff[i] + gy0 * HW_]);

    // ---- register prefetch: ring row gy0+4 (always in-image), K row gy0+1
    float rr0[FSPT], rr1[FSPT], krf[KSPT];
    {
        const int yr = gy0 + 4;
#pragma unroll
        for (int i = 0; i < FSPT; ++i) {
            rr0[i] = 0.f; rr1[i] = 0.f;
            if (fm0[i]) rr0[i] = Fb[(size_t)yr * HW_ + fgof[i]];
            if (fm1[i]) rr1[i] = Fb[(size_t)yr * HW_ + fgof[i] + 1];
        }
#pragma unroll
        for (int i = 0; i < KSPT; ++i)
            krf[i] = (kldsoff[i] >= 0) ? Kb[kgoff[i] + (gy0 + 1) * HW_] : 0.f;
    }

    const int kcl8 = (kb == 3) ? 0 : kb * 8;   // kb=3: B=0, clamp A read in-row
    const int aoffc = (ch * 48 + n) * XPITCH + nt * 16 + kcl8;
    float* ob = O_ + ((size_t)(b * CHAN + ch * 48 + kb * 4)) * HWPIX
              + gx0 + nt * 16 + n;
    const short8v bzero = {0, 0, 0, 0, 0, 0, 0, 0};

#pragma unroll 1
    for (int t = 0; t < YT; ++t) {
        const int y = gy0 + t;
        __syncthreads();   // prev-iter writes visible; all prev reads drained

        // B fragments: 7x ds_read_b128 from BT[t&1] (2-way banks = free)
        const short* btp = BT + (t & 1) * BT_BUF + nt * BT_STRIP + n * BT_NROW + kb * 8;
        short8v bfr[KS];
#pragma unroll
        for (int dy = 0; dy < KS; ++dy)
            bfr[dy] = (kb < 3) ? *(const short8v*)(btp + dy * BT_K) : bzero;

        // A reads + MFMA (3 c-tiles, dy-chained accumulators)
        f32x4 acc0 = {0,0,0,0}, acc1 = {0,0,0,0}, acc2 = {0,0,0,0};
#pragma unroll
        for (int dy = 0; dy < KS; ++dy) {
            const short* ap = lds + ((y + dy - 3) & 7) * ROWSTRIDE + aoffc;
            acc0 = __builtin_amdgcn_mfma_f32_16x16x32_bf16(*(const short8v*)(ap), bfr[dy], acc0, 0, 0, 0);
            acc1 = __builtin_amdgcn_mfma_f32_16x16x32_bf16(*(const short8v*)(ap + 16 * XPITCH), bfr[dy], acc1, 0, 0, 0);
            acc2 = __builtin_amdgcn_mfma_f32_16x16x32_bf16(*(const short8v*)(ap + 32 * XPITCH), bfr[dy], acc2, 0, 0, 0);
        }

        // stores: D col = lane&15 (px), row = kb*4+r (channel)
        {
            float* op = ob + (size_t)y * HW_;
#pragma unroll
            for (int r = 0; r < 4; ++r) {
                op[(size_t)r * HWPIX]        = acc0[r];
                op[(size_t)(16 + r) * HWPIX] = acc1[r];
                op[(size_t)(32 + r) * HWPIX] = acc2[r];
            }
        }

        if (t < YT - 1) {
            // ring row y+4 (slot disjoint from all rows read this phase)
            int rbase = ((y + 4) & 7) * ROWSTRIDE;
#pragma unroll
            for (int i = 0; i < FSPT; ++i)
                if (fldsoff[i] >= 0)
                    lds32[(rbase + fldsoff[i]) >> 1] =
                        (unsigned)f2bf(rr0[i]) | ((unsigned)f2bf(rr1[i]) << 16);
            // BT[(t+1)&1] for row y+1 (opposite buffer from this phase's reads)
            short* btw = BT + ((t + 1) & 1) * BT_BUF;
#pragma unroll
            for (int i = 0; i < KSPT; ++i)
                if (kldsoff[i] >= 0) btw[kldsoff[i]] = (short)f2bf(krf[i]);
        }

        // issue next prefetches; they fly across the next barrier (T14)
        if (t < YT - 2) {
            int yr = y + 5;
            bool yok = ((unsigned)yr < (unsigned)HW_);
#pragma unroll
            for (int i = 0; i < FSPT; ++i) {
                rr0[i] = 0.f; rr1[i] = 0.f;
                if (yok && fm0[i]) rr0[i] = Fb[(size_t)yr * HW_ + fgof[i]];
                if (yok && fm1[i]) rr1[i] = Fb[(size_t)yr * HW_ + fgof[i] + 1];
            }
            const int yk = y + 2;   // <= gy0+15 <= 255
#pragma unroll
            for (int i = 0; i < KSPT; ++i)
                if (kldsoff[i] >= 0) krf[i] = Kb[kgoff[i] + yk * HW_];
        }
    }
}

extern "C" void kernel_launch(void* const* d_in, const int* in_sizes, int n_in,
                              void* d_out, int out_size, void* d_ws, size_t ws_size,
                              hipStream_t stream) {
    const float* kernels  = (const float*)d_in[0];  // [4,7,7,256,256]
    const float* features = (const float*)d_in[1];  // [4,96,256,256]
    float* out = (float*)d_out;                     // [4,96,256,256]

    hipFuncSetAttribute(reinterpret_cast<const void*>(&svconv_mfma2),
                        hipFuncAttributeMaxDynamicSharedMemorySize, LDS_BYTES);

    dim3 grid(HW_ / XT, HW_ / YT, BATCH);  // (4, 16, 4) = 256 blocks = 1/CU
    dim3 block(NTHR);
    svconv_mfma2<<<grid, block, LDS_BYTES, stream>>>(kernels, features, out);
}